// Round 2
// baseline (2356.769 us; speedup 1.0000x reference)
//
#include <hip/hip_runtime.h>

#define BATCH   32768
#define DIM     256
#define NCODES  8192
#define BETA    0.25f

// ---- argmin kernel tiling ----
#define ROWS_T     64           // rows per block
#define CODES_T    128          // codes per block tile
#define KC         32           // K-chunk staged in LDS
#define K4_PER_KC  (KC / 4)     // 8 float4 steps per chunk
#define LDS_STRIDE 36           // floats; 144 B = 9 x 16B units -> worst 2-way (free)

// ============================================================================
// Kernel A: row sums-of-squares for BOTH codebook (e2[k]) and z (z2[b]);
// one wave per row. Also zeroes the loss accumulator (d_ws poisoned 0xAA).
// items [0, NCODES) -> codebook rows; [NCODES, NCODES+BATCH) -> z rows.
// ============================================================================
__global__ void vq_sq_kernel(const float* __restrict__ z,
                             const float* __restrict__ cb,
                             float* __restrict__ e2,
                             float* __restrict__ z2,
                             float* __restrict__ loss_acc) {
    const int lane = threadIdx.x & 63;
    const int wid  = threadIdx.x >> 6;
    const int item = blockIdx.x * 4 + wid;
    const float* src;
    if (item < NCODES) src = cb + (size_t)item * DIM;
    else               src = z  + (size_t)(item - NCODES) * DIM;
    const float4 v = *(const float4*)(src + lane * 4);
    float s = v.x * v.x + v.y * v.y + v.z * v.z + v.w * v.w;
    #pragma unroll
    for (int off = 32; off > 0; off >>= 1) s += __shfl_down(s, off, 64);
    if (lane == 0) {
        if (item < NCODES) e2[item] = s;
        else               z2[item - NCODES] = s;
    }
    if (blockIdx.x == 0 && threadIdx.x == 0) *loss_acc = 0.0f;
}

// ============================================================================
// Kernel B: fused distance-GEMM + argmin, mirroring the reference's fp32
// rounding:  dist = fl( fl(z2 + e2[k]) - 2*ze )   (2*ze exact; one final
// rounding -- fma contraction of S - 2*acc is the same single rounding).
// Ties on the coarse grid broken toward the LOWEST index (np.argmin).
// Block tile: 64 rows x 8192 codes (128 at a time), K chunked by 32.
// Thread (tx,ty)=(t&15,t>>4) owns rows {ty+16i} x codes {tx+16j}.
// ============================================================================
__launch_bounds__(256, 2)
__global__ void vq_argmin_kernel(const float* __restrict__ z,
                                 const float* __restrict__ cb,
                                 const float* __restrict__ e2g,
                                 const float* __restrict__ z2g,
                                 float* __restrict__ idx_out_f) {
    __shared__ float zs[ROWS_T * LDS_STRIDE];
    __shared__ float es[CODES_T * LDS_STRIDE];
    __shared__ float e2s[CODES_T];
    __shared__ float z2s[ROWS_T];

    const int t  = threadIdx.x;
    const int tx = t & 15;
    const int ty = t >> 4;
    const int row0 = blockIdx.x * ROWS_T;

    if (t < ROWS_T) z2s[t] = z2g[row0 + t];   // barrier below covers this

    float minv[4];
    int   mini[4];
    #pragma unroll
    for (int i = 0; i < 4; ++i) { minv[i] = 3.4e38f; mini[i] = 0; }

    for (int ct = 0; ct < NCODES / CODES_T; ++ct) {
        float acc[4][8];
        #pragma unroll
        for (int i = 0; i < 4; ++i)
            #pragma unroll
            for (int j = 0; j < 8; ++j) acc[i][j] = 0.0f;

        for (int kc = 0; kc < DIM; kc += KC) {
            __syncthreads();
            // stage z tile: 64 rows x 32 floats = 512 float4
            #pragma unroll
            for (int l = 0; l < 2; ++l) {
                const int idx = l * 256 + t;
                const int r   = idx >> 3;
                const int k4  = idx & 7;
                *(float4*)(zs + r * LDS_STRIDE + k4 * 4) =
                    *(const float4*)(z + (size_t)(row0 + r) * DIM + kc + k4 * 4);
            }
            // stage e tile: 128 codes x 32 floats = 1024 float4
            #pragma unroll
            for (int l = 0; l < 4; ++l) {
                const int idx = l * 256 + t;
                const int r   = idx >> 3;
                const int k4  = idx & 7;
                *(float4*)(es + r * LDS_STRIDE + k4 * 4) =
                    *(const float4*)(cb + (size_t)(ct * CODES_T + r) * DIM + kc + k4 * 4);
            }
            if (kc == 0 && t < CODES_T) e2s[t] = e2g[ct * CODES_T + t];
            __syncthreads();

            #pragma unroll
            for (int k4 = 0; k4 < K4_PER_KC; ++k4) {
                float4 zf[4], ef[8];
                #pragma unroll
                for (int i = 0; i < 4; ++i)
                    zf[i] = *(const float4*)(zs + (ty + 16 * i) * LDS_STRIDE + k4 * 4);
                #pragma unroll
                for (int j = 0; j < 8; ++j)
                    ef[j] = *(const float4*)(es + (tx + 16 * j) * LDS_STRIDE + k4 * 4);
                #pragma unroll
                for (int i = 0; i < 4; ++i)
                    #pragma unroll
                    for (int j = 0; j < 8; ++j) {
                        acc[i][j] = fmaf(zf[i].x, ef[j].x, acc[i][j]);
                        acc[i][j] = fmaf(zf[i].y, ef[j].y, acc[i][j]);
                        acc[i][j] = fmaf(zf[i].z, ef[j].z, acc[i][j]);
                        acc[i][j] = fmaf(zf[i].w, ef[j].w, acc[i][j]);
                    }
            }
        }
        // scores, quantized exactly like the reference: S = fl(z2 + e2),
        // dist = fl(S - 2*ze). Ascending-gidx scan + strict < keeps the
        // earliest (lowest) index on exact ties within a thread.
        #pragma unroll
        for (int j = 0; j < 8; ++j) {
            const int c     = tx + 16 * j;
            const float e2v = e2s[c];
            const int gidx  = ct * CODES_T + c;
            #pragma unroll
            for (int i = 0; i < 4; ++i) {
                const float S     = z2s[ty + 16 * i] + e2v;   // rounded add
                const float score = S - 2.0f * acc[i][j];     // single rounding
                if (score < minv[i]) { minv[i] = score; mini[i] = gidx; }
            }
        }
    }

    // cross-thread reduction: 16 tx threads share each row; lexicographic
    // (val, idx) min gives argmin-first-index semantics.
    __syncthreads();
    float* rv = zs;          // reuse LDS: 64*16 floats
    int*   ri = (int*)es;
    #pragma unroll
    for (int i = 0; i < 4; ++i) {
        const int r = ty + 16 * i;
        rv[r * 16 + tx] = minv[i];
        ri[r * 16 + tx] = mini[i];
    }
    __syncthreads();
    if (t < ROWS_T) {
        float bv = rv[t * 16];
        int   bi = ri[t * 16];
        #pragma unroll
        for (int x = 1; x < 16; ++x) {
            const float v  = rv[t * 16 + x];
            const int   ii = ri[t * 16 + x];
            if (v < bv || (v == bv && ii < bi)) { bv = v; bi = ii; }
        }
        idx_out_f[row0 + t] = (float)bi;   // out buffer is fp32; 8191 exact
    }
}

// ============================================================================
// Kernel C: z_q_st = fl(z_e + fl(z_q - z_e))  (elementwise mirror of the
// reference's straight-through expression) + squared-error sum for the loss.
// One wave per row; one atomicAdd per block. Index read back from d_out
// (float, exact up to 8191).
// ============================================================================
__global__ void vq_gather_loss_kernel(const float* __restrict__ z,
                                      const float* __restrict__ cb,
                                      const float* __restrict__ idx_f,
                                      float* __restrict__ zq_out,
                                      float* __restrict__ loss_acc) {
    const int lane = threadIdx.x & 63;
    const int wid  = threadIdx.x >> 6;
    const int row  = blockIdx.x * 4 + wid;
    const int k = (int)idx_f[row];
    const float4 e  = *(const float4*)(cb + (size_t)k * DIM + lane * 4);
    const float4 zv = *(const float4*)(z + (size_t)row * DIM + lane * 4);
    const float dx = e.x - zv.x, dy = e.y - zv.y, dz = e.z - zv.z, dw = e.w - zv.w;
    float4 o;
    o.x = zv.x + dx; o.y = zv.y + dy; o.z = zv.z + dz; o.w = zv.w + dw;
    *(float4*)(zq_out + (size_t)row * DIM + lane * 4) = o;
    float s = dx * dx + dy * dy + dz * dz + dw * dw;
    #pragma unroll
    for (int off = 32; off > 0; off >>= 1) s += __shfl_down(s, off, 64);
    __shared__ float wsum[4];
    if (lane == 0) wsum[wid] = s;
    __syncthreads();
    if (threadIdx.x == 0)
        atomicAdd(loss_acc, wsum[0] + wsum[1] + wsum[2] + wsum[3]);
}

// ============================================================================
// Kernel D: finalize scalars. Forward values: cb_loss == commit_loss == mean,
// vq_loss = mean + 0.25*mean (mirror the reference's add order).
// ============================================================================
__global__ void vq_finalize_kernel(const float* __restrict__ loss_acc,
                                   float* __restrict__ out_losses) {
    const float mean = *loss_acc * (1.0f / (float)(BATCH * DIM));  // /2^23 exact
    out_losses[0] = mean + BETA * mean;    // vq_loss
    out_losses[1] = mean;                  // cb_loss
    out_losses[2] = mean;                  // commit_loss
}

// ============================================================================
extern "C" void kernel_launch(void* const* d_in, const int* in_sizes, int n_in,
                              void* d_out, int out_size, void* d_ws, size_t ws_size,
                              hipStream_t stream) {
    const float* z  = (const float*)d_in[0];   // [32768, 256] fp32
    const float* cb = (const float*)d_in[1];   // [8192, 256]  fp32

    float* out    = (float*)d_out;
    float* zq     = out;                                   // [32768*256]
    float* idx_f  = out + (size_t)BATCH * DIM;             // [32768]
    float* losses = out + (size_t)BATCH * DIM + BATCH;     // [3]

    // workspace layout (floats): [0..8) loss acc, [8..8+NCODES) e2, then z2
    float* ws  = (float*)d_ws;
    float* acc = ws;
    float* e2  = ws + 8;
    float* z2  = ws + 8 + NCODES;

    vq_sq_kernel<<<(NCODES + BATCH) / 4, 256, 0, stream>>>(z, cb, e2, z2, acc);
    vq_argmin_kernel<<<BATCH / ROWS_T, 256, 0, stream>>>(z, cb, e2, z2, idx_f);
    vq_gather_loss_kernel<<<BATCH / 4, 256, 0, stream>>>(z, cb, idx_f, zq, acc);
    vq_finalize_kernel<<<1, 1, 0, stream>>>(acc, losses);
}

// Round 3
// 1550.119 us; speedup vs baseline: 1.5204x; 1.5204x over previous
//
#include <hip/hip_runtime.h>

#define BATCH   32768
#define DIM     256
#define NCODES  8192
#define BETA    0.25f
#define EPS     3e-4f   // screen window: grid-tie ulp(512)=6.1e-5 + 2*delta(bf16 screen, 20+ sigma)

typedef unsigned short ushort_t;
typedef unsigned char  uchar_t;
typedef __attribute__((ext_vector_type(8))) short bf16x8;
typedef __attribute__((ext_vector_type(4))) float f32x4;

// async global->LDS, 16B per lane; dest = wave-uniform base + lane*16
#define GLOAD16(gp, lp) __builtin_amdgcn_global_load_lds( \
    (const __attribute__((address_space(1))) void*)(gp), \
    (__attribute__((address_space(3))) void*)(lp), 16, 0, 0)

__device__ inline ushort_t f2bf(float f) {  // RNE float->bf16 (no NaN in data)
    union { float f; unsigned u; } v; v.f = f;
    return (ushort_t)((v.u + 0x7FFF + ((v.u >> 16) & 1)) >> 16);
}

// ============================================================================
// Kernel A: fused prep. One wave per row (codebook rows then z rows):
// e2[k]/z2[b] row sums-of-squares (fp32, same as R2) + bf16 copies eh/zh.
// Also zeroes the loss accumulator (d_ws is poisoned 0xAA every launch).
// ============================================================================
__global__ void vq_prep_kernel(const float* __restrict__ z,
                               const float* __restrict__ cb,
                               float* __restrict__ e2, float* __restrict__ z2,
                               ushort_t* __restrict__ eh, ushort_t* __restrict__ zh,
                               float* __restrict__ loss_acc) {
    const int lane = threadIdx.x & 63;
    const int wid  = threadIdx.x >> 6;
    const int item = blockIdx.x * 4 + wid;
    const float* src;
    ushort_t* dst;
    if (item < NCODES) { src = cb + (size_t)item * DIM;            dst = eh + (size_t)item * DIM; }
    else               { src = z  + (size_t)(item - NCODES) * DIM; dst = zh + (size_t)(item - NCODES) * DIM; }
    const float4 v = *(const float4*)(src + lane * 4);
    ushort4 b; b.x = f2bf(v.x); b.y = f2bf(v.y); b.z = f2bf(v.z); b.w = f2bf(v.w);
    *(ushort4*)(dst + lane * 4) = b;
    float s = v.x * v.x + v.y * v.y + v.z * v.z + v.w * v.w;
    #pragma unroll
    for (int off = 32; off > 0; off >>= 1) s += __shfl_down(s, off, 64);
    if (lane == 0) {
        if (item < NCODES) e2[item] = s;
        else               z2[item - NCODES] = s;
    }
    if (blockIdx.x == 0 && threadIdx.x == 0) *loss_acc = 0.0f;
}

// ============================================================================
// Kernel B: MFMA screen. approx score s = e2[c] - 2 * (zh . eh)   (bf16 MFMA,
// fp32 accum). Block: 64 rows x 8192 codes (512/ct-iter, 4 waves x 128 codes).
// Emits per (row, 128-code tile): tilemin (fp32) and a 128-bit mask of codes
// with s <= tilemin + EPS. Masks stored in d_out's zq region (1 KB/row),
// overwritten later by the gather kernel.
// Fragment layouts (verified m89/m120): A[m=lane&15][k=(lane>>4)*8+j],
// B[n=lane&15][k=(lane>>4)*8+j], C/D col=lane&15, row=(lane>>4)*4+reg.
// LDS tiles are 16-row x 32-k linear => ds_read_b128 is 64x16B fully dense
// (conflict-free) and global_load_lds's lane*16 dest order matches exactly.
// ============================================================================
__launch_bounds__(256, 2)
__global__ void vq_screen_kernel(const ushort_t* __restrict__ zh_g,
                                 const ushort_t* __restrict__ eh_g,
                                 const float* __restrict__ e2g,
                                 float* __restrict__ tilemin_g,
                                 uchar_t* __restrict__ mask_g) {
    __shared__ ushort_t zh_s[64 * 32];    // 4 row-tiles of [16][32]
    __shared__ ushort_t eh_s[512 * 32];   // 32 code-tiles of [16][32]
    __shared__ float    e2_s[512];

    const int t    = threadIdx.x;
    const int w    = t >> 6;        // wave 0..3
    const int lane = t & 63;
    const int c    = lane & 15;     // MFMA col / fragment row
    const int q    = lane >> 4;     // MFMA quad
    const int row0 = blockIdx.x * 64;

    for (int ct = 0; ct < 16; ++ct) {
        __syncthreads();                       // prev epilogue done before e2_s restage
        e2_s[t]       = e2g[ct * 512 + t];
        e2_s[256 + t] = e2g[ct * 512 + 256 + t];

        f32x4 acc[4][8];
        #pragma unroll
        for (int i = 0; i < 4; ++i)
            #pragma unroll
            for (int j = 0; j < 8; ++j) acc[i][j] = (f32x4)0.0f;

        for (int kc = 0; kc < 256; kc += 32) {
            __syncthreads();                   // prev chunk's frag reads done
            // stage zh row-tile w: 16 rows x 32 k
            GLOAD16(zh_g + (size_t)(row0 + w * 16 + (lane >> 2)) * DIM + kc + (lane & 3) * 8,
                    &zh_s[w * 512]);
            // stage 8 eh code-tiles
            #pragma unroll
            for (int s8 = 0; s8 < 8; ++s8) {
                const int c16 = w * 8 + s8;
                GLOAD16(eh_g + (size_t)(ct * 512 + c16 * 16 + (lane >> 2)) * DIM + kc + (lane & 3) * 8,
                        &eh_s[c16 * 512]);
            }
            __syncthreads();                   // vmcnt(0) drain + visibility

            bf16x8 a[4], b[8];
            #pragma unroll
            for (int i = 0; i < 4; ++i)
                a[i] = *(const bf16x8*)&zh_s[i * 512 + c * 32 + q * 8];
            #pragma unroll
            for (int j = 0; j < 8; ++j)
                b[j] = *(const bf16x8*)&eh_s[(w * 8 + j) * 512 + c * 32 + q * 8];
            #pragma unroll
            for (int i = 0; i < 4; ++i)
                #pragma unroll
                for (int j = 0; j < 8; ++j)
                    acc[i][j] = __builtin_amdgcn_mfma_f32_16x16x32_bf16(a[i], b[j], acc[i][j], 0, 0, 0);
        }

        // epilogue: scores (reuse acc regs), per-row 128-tile min, mask bits
        float tm[4][4];                        // [i][reg] = j-min
        #pragma unroll
        for (int i = 0; i < 4; ++i)
            #pragma unroll
            for (int reg = 0; reg < 4; ++reg) tm[i][reg] = 3.4e38f;
        #pragma unroll
        for (int i = 0; i < 4; ++i)
            #pragma unroll
            for (int j = 0; j < 8; ++j) {
                const float e2v = e2_s[w * 128 + j * 16 + c];
                #pragma unroll
                for (int reg = 0; reg < 4; ++reg) {
                    const float s = fmaf(-2.0f, acc[i][j][reg], e2v);
                    acc[i][j][reg] = s;
                    tm[i][reg] = fminf(tm[i][reg], s);
                }
            }
        // butterfly over the 16 col-lanes (xor masks <16 keep q intact)
        #pragma unroll
        for (int st = 1; st < 16; st <<= 1)
            #pragma unroll
            for (int i = 0; i < 4; ++i)
                #pragma unroll
                for (int reg = 0; reg < 4; ++reg)
                    tm[i][reg] = fminf(tm[i][reg], __shfl_xor(tm[i][reg], st, 64));

        const int tile = ct * 4 + w;
        #pragma unroll
        for (int i = 0; i < 4; ++i)
            #pragma unroll
            for (int reg = 0; reg < 4; ++reg) {
                const int row = row0 + i * 16 + q * 4 + reg;
                const float thr = tm[i][reg] + EPS;
                unsigned m8 = 0;
                #pragma unroll
                for (int j = 0; j < 8; ++j)
                    m8 |= (unsigned)(acc[i][j][reg] <= thr) << j;
                mask_g[(size_t)row * 1024 + tile * 16 + c] = (uchar_t)m8;
                if (c == 0) tilemin_g[(size_t)row * 64 + tile] = tm[i][reg];
            }
    }
}

// ============================================================================
// Kernel C: exact select. One thread per row: flag tiles with
// tilemin <= gmin + EPS, exact-eval masked codes with R2's bit-identical
// numerics (ascending-k sequential fmaf; S = fl(z2+e2); score = fl(S-2acc);
// ascending-code strict < => lowest index on grid ties).
// ============================================================================
__global__ void vq_select_kernel(const float* __restrict__ z,
                                 const float* __restrict__ cb,
                                 const float* __restrict__ e2g,
                                 const float* __restrict__ z2g,
                                 const float* __restrict__ tilemin_g,
                                 const uchar_t* __restrict__ mask_g,
                                 float* __restrict__ idx_out_f) {
    const int row = blockIdx.x * 256 + threadIdx.x;
    const float* tmr = tilemin_g + (size_t)row * 64;
    float gmin = 3.4e38f;
    for (int t = 0; t < 64; ++t) gmin = fminf(gmin, tmr[t]);
    const float thr = gmin + EPS;
    const float z2v = z2g[row];
    const float* zr = z + (size_t)row * DIM;

    float bv = 3.4e38f;
    int   bi = 0;
    for (int t = 0; t < 64; ++t) {
        if (tmr[t] > thr) continue;
        const uchar_t* mb = mask_g + (size_t)row * 1024 + t * 16;
        const unsigned long long m0 = *(const unsigned long long*)(mb);
        const unsigned long long m1 = *(const unsigned long long*)(mb + 8);
        for (int col = 0; col < 128; ++col) {       // ascending code order
            const int cc = col & 15, jj = col >> 4;
            const unsigned long long mw = (cc < 8) ? m0 : m1;
            if (!((mw >> ((cc & 7) * 8 + jj)) & 1ull)) continue;
            const int code = t * 128 + col;
            const float* er = cb + (size_t)code * DIM;
            float acc = 0.0f;
            for (int k = 0; k < DIM; ++k) acc = fmaf(zr[k], er[k], acc);
            const float S  = z2v + e2g[code];
            const float sc = fmaf(-2.0f, acc, S);
            if (sc < bv) { bv = sc; bi = code; }
        }
    }
    idx_out_f[row] = (float)bi;
}

// ============================================================================
// Kernel D: z_q_st = fl(z_e + fl(z_q - z_e)) + squared-error sum (as R2).
// ============================================================================
__global__ void vq_gather_loss_kernel(const float* __restrict__ z,
                                      const float* __restrict__ cb,
                                      const float* __restrict__ idx_f,
                                      float* __restrict__ zq_out,
                                      float* __restrict__ loss_acc) {
    const int lane = threadIdx.x & 63;
    const int wid  = threadIdx.x >> 6;
    const int row  = blockIdx.x * 4 + wid;
    const int k = (int)idx_f[row];
    const float4 e  = *(const float4*)(cb + (size_t)k * DIM + lane * 4);
    const float4 zv = *(const float4*)(z + (size_t)row * DIM + lane * 4);
    const float dx = e.x - zv.x, dy = e.y - zv.y, dz = e.z - zv.z, dw = e.w - zv.w;
    float4 o;
    o.x = zv.x + dx; o.y = zv.y + dy; o.z = zv.z + dz; o.w = zv.w + dw;
    *(float4*)(zq_out + (size_t)row * DIM + lane * 4) = o;
    float s = dx * dx + dy * dy + dz * dz + dw * dw;
    #pragma unroll
    for (int off = 32; off > 0; off >>= 1) s += __shfl_down(s, off, 64);
    __shared__ float wsum[4];
    if (lane == 0) wsum[wid] = s;
    __syncthreads();
    if (threadIdx.x == 0)
        atomicAdd(loss_acc, wsum[0] + wsum[1] + wsum[2] + wsum[3]);
}

// ============================================================================
// Kernel E: finalize scalars.
// ============================================================================
__global__ void vq_finalize_kernel(const float* __restrict__ loss_acc,
                                   float* __restrict__ out_losses) {
    const float mean = *loss_acc * (1.0f / (float)(BATCH * DIM));  // /2^23 exact
    out_losses[0] = mean + BETA * mean;    // vq_loss
    out_losses[1] = mean;                  // cb_loss
    out_losses[2] = mean;                  // commit_loss
}

// ============================================================================
extern "C" void kernel_launch(void* const* d_in, const int* in_sizes, int n_in,
                              void* d_out, int out_size, void* d_ws, size_t ws_size,
                              hipStream_t stream) {
    const float* z  = (const float*)d_in[0];   // [32768, 256] fp32
    const float* cb = (const float*)d_in[1];   // [8192, 256]  fp32

    float* out    = (float*)d_out;
    float* zq     = out;                                   // [32768*256]
    float* idx_f  = out + (size_t)BATCH * DIM;             // [32768]
    float* losses = out + (size_t)BATCH * DIM + BATCH;     // [3]
    uchar_t* mask = (uchar_t*)d_out;                       // zq region reused: 1 KB/row

    // workspace layout (floats): acc | e2 | z2 | tilemin | zh (ushort) | eh (ushort)
    float* ws       = (float*)d_ws;
    float* acc      = ws;                                  // 256 floats (pad)
    float* e2       = ws + 256;                            // 8192
    float* z2       = e2 + NCODES;                         // 32768
    float* tilemin  = z2 + BATCH;                          // 32768*64
    ushort_t* zh    = (ushort_t*)(tilemin + (size_t)BATCH * 64);   // 32768*256
    ushort_t* eh    = zh + (size_t)BATCH * DIM;            // 8192*256

    vq_prep_kernel<<<(NCODES + BATCH) / 4, 256, 0, stream>>>(z, cb, e2, z2, eh, zh, acc);
    vq_screen_kernel<<<BATCH / 64, 256, 0, stream>>>(zh, eh, e2, tilemin, mask);
    vq_select_kernel<<<BATCH / 256, 256, 0, stream>>>(z, cb, e2, z2, tilemin, mask, idx_f);
    vq_gather_loss_kernel<<<BATCH / 4, 256, 0, stream>>>(z, cb, idx_f, zq, acc);
    vq_finalize_kernel<<<1, 1, 0, stream>>>(acc, losses);
}

// Round 4
// 910.980 us; speedup vs baseline: 2.5871x; 1.7016x over previous
//
#include <hip/hip_runtime.h>

#define BATCH   32768
#define DIM     256
#define NCODES  8192
#define BETA    0.25f
#define EPS     3e-4f   // screen window: grid-tie ulp + 2*delta(bf16 screen, 20+ sigma)
#define WL_CAP  (1u << 20)

typedef unsigned short ushort_t;
typedef unsigned char  uchar_t;
typedef unsigned long long u64;
typedef __attribute__((ext_vector_type(8))) short bf16x8;
typedef __attribute__((ext_vector_type(4))) float f32x4;

// async global->LDS, 16B per lane; dest = wave-uniform base + lane*16
#define GLOAD16(gp, lp) __builtin_amdgcn_global_load_lds( \
    (const __attribute__((address_space(1))) void*)(gp), \
    (__attribute__((address_space(3))) void*)(lp), 16, 0, 0)

__device__ inline ushort_t f2bf(float f) {  // RNE float->bf16 (no NaN in data)
    union { float f; unsigned u; } v; v.f = f;
    return (ushort_t)((v.u + 0x7FFF + ((v.u >> 16) & 1)) >> 16);
}

// ============================================================================
// Kernel A: fused prep. One wave per row (codebook rows then z rows):
// e2[k]/z2[b] row sums-of-squares + bf16 copies eh/zh. Zeroes loss acc and
// the worklist counter (d_ws is poisoned 0xAA every launch).
// ============================================================================
__global__ void vq_prep_kernel(const float* __restrict__ z,
                               const float* __restrict__ cb,
                               float* __restrict__ e2, float* __restrict__ z2,
                               ushort_t* __restrict__ eh, ushort_t* __restrict__ zh,
                               float* __restrict__ loss_acc,
                               unsigned* __restrict__ wl_cnt) {
    const int lane = threadIdx.x & 63;
    const int wid  = threadIdx.x >> 6;
    const int item = blockIdx.x * 4 + wid;
    const float* src;
    ushort_t* dst;
    if (item < NCODES) { src = cb + (size_t)item * DIM;            dst = eh + (size_t)item * DIM; }
    else               { src = z  + (size_t)(item - NCODES) * DIM; dst = zh + (size_t)(item - NCODES) * DIM; }
    const float4 v = *(const float4*)(src + lane * 4);
    ushort4 b; b.x = f2bf(v.x); b.y = f2bf(v.y); b.z = f2bf(v.z); b.w = f2bf(v.w);
    *(ushort4*)(dst + lane * 4) = b;
    float s = v.x * v.x + v.y * v.y + v.z * v.z + v.w * v.w;
    #pragma unroll
    for (int off = 32; off > 0; off >>= 1) s += __shfl_down(s, off, 64);
    if (lane == 0) {
        if (item < NCODES) e2[item] = s;
        else               z2[item - NCODES] = s;
    }
    if (blockIdx.x == 0 && threadIdx.x == 0) { *loss_acc = 0.0f; *wl_cnt = 0u; }
}

// ============================================================================
// Kernel B: MFMA screen (unchanged structure from R3). approx score
// s = e2[c] - 2*(zh.eh), bf16 MFMA fp32-acc. Per (row, 128-code tile):
// tilemin (TRANSPOSED layout [tile][row] for coalesced reads downstream)
// and a 128-bit mask of codes with s <= tilemin + EPS (in d_out's zq region,
// overwritten later by the gather kernel).
// ============================================================================
__launch_bounds__(256, 2)
__global__ void vq_screen_kernel(const ushort_t* __restrict__ zh_g,
                                 const ushort_t* __restrict__ eh_g,
                                 const float* __restrict__ e2g,
                                 float* __restrict__ tilemin_g,
                                 uchar_t* __restrict__ mask_g) {
    __shared__ ushort_t zh_s[64 * 32];    // 4 row-tiles of [16][32]
    __shared__ ushort_t eh_s[512 * 32];   // 32 code-tiles of [16][32]
    __shared__ float    e2_s[512];

    const int t    = threadIdx.x;
    const int w    = t >> 6;        // wave 0..3
    const int lane = t & 63;
    const int c    = lane & 15;     // MFMA col / fragment row
    const int q    = lane >> 4;     // MFMA quad
    const int row0 = blockIdx.x * 64;

    for (int ct = 0; ct < 16; ++ct) {
        __syncthreads();                       // prev epilogue done before e2_s restage
        e2_s[t]       = e2g[ct * 512 + t];
        e2_s[256 + t] = e2g[ct * 512 + 256 + t];

        f32x4 acc[4][8];
        #pragma unroll
        for (int i = 0; i < 4; ++i)
            #pragma unroll
            for (int j = 0; j < 8; ++j) acc[i][j] = (f32x4)0.0f;

        for (int kc = 0; kc < 256; kc += 32) {
            __syncthreads();                   // prev chunk's frag reads done
            GLOAD16(zh_g + (size_t)(row0 + w * 16 + (lane >> 2)) * DIM + kc + (lane & 3) * 8,
                    &zh_s[w * 512]);
            #pragma unroll
            for (int s8 = 0; s8 < 8; ++s8) {
                const int c16 = w * 8 + s8;
                GLOAD16(eh_g + (size_t)(ct * 512 + c16 * 16 + (lane >> 2)) * DIM + kc + (lane & 3) * 8,
                        &eh_s[c16 * 512]);
            }
            __syncthreads();                   // vmcnt(0) drain + visibility

            bf16x8 a[4], b[8];
            #pragma unroll
            for (int i = 0; i < 4; ++i)
                a[i] = *(const bf16x8*)&zh_s[i * 512 + c * 32 + q * 8];
            #pragma unroll
            for (int j = 0; j < 8; ++j)
                b[j] = *(const bf16x8*)&eh_s[(w * 8 + j) * 512 + c * 32 + q * 8];
            #pragma unroll
            for (int i = 0; i < 4; ++i)
                #pragma unroll
                for (int j = 0; j < 8; ++j)
                    acc[i][j] = __builtin_amdgcn_mfma_f32_16x16x32_bf16(a[i], b[j], acc[i][j], 0, 0, 0);
        }

        // epilogue: scores, per-row tile min, mask bits
        float tm[4][4];
        #pragma unroll
        for (int i = 0; i < 4; ++i)
            #pragma unroll
            for (int reg = 0; reg < 4; ++reg) tm[i][reg] = 3.4e38f;
        #pragma unroll
        for (int i = 0; i < 4; ++i)
            #pragma unroll
            for (int j = 0; j < 8; ++j) {
                const float e2v = e2_s[w * 128 + j * 16 + c];
                #pragma unroll
                for (int reg = 0; reg < 4; ++reg) {
                    const float s = fmaf(-2.0f, acc[i][j][reg], e2v);
                    acc[i][j][reg] = s;
                    tm[i][reg] = fminf(tm[i][reg], s);
                }
            }
        #pragma unroll
        for (int st = 1; st < 16; st <<= 1)
            #pragma unroll
            for (int i = 0; i < 4; ++i)
                #pragma unroll
                for (int reg = 0; reg < 4; ++reg)
                    tm[i][reg] = fminf(tm[i][reg], __shfl_xor(tm[i][reg], st, 64));

        const int tile = ct * 4 + w;
        #pragma unroll
        for (int i = 0; i < 4; ++i)
            #pragma unroll
            for (int reg = 0; reg < 4; ++reg) {
                const int row = row0 + i * 16 + q * 4 + reg;
                const float thr = tm[i][reg] + EPS;
                unsigned m8 = 0;
                #pragma unroll
                for (int j = 0; j < 8; ++j)
                    m8 |= (unsigned)(acc[i][j][reg] <= thr) << j;
                mask_g[(size_t)row * 1024 + tile * 16 + c] = (uchar_t)m8;
                if (c == 0) tilemin_g[(size_t)tile * BATCH + row] = tm[i][reg];
            }
    }
}

// ============================================================================
// Kernel C: candidate emission. One thread per row: gmin over 64 tile-mins
// (coalesced: tilemin is [tile][row]), flag tiles within EPS, enumerate mask
// bits via ctz, emit (row<<13|code) to the worklist. Also init per-row packed
// best (score_bits<<32 | code) to all-ones.
// ============================================================================
__global__ void vq_candidates_kernel(const float* __restrict__ tilemin_g,
                                     const uchar_t* __restrict__ mask_g,
                                     unsigned* __restrict__ wl,
                                     unsigned* __restrict__ wl_cnt,
                                     u64* __restrict__ packed_best) {
    const int row = blockIdx.x * 256 + threadIdx.x;
    packed_best[row] = ~0ull;
    float gmin = 3.4e38f;
    #pragma unroll 8
    for (int t = 0; t < 64; ++t)
        gmin = fminf(gmin, tilemin_g[(size_t)t * BATCH + row]);
    const float thr = gmin + EPS;
    for (int t = 0; t < 64; ++t) {
        if (tilemin_g[(size_t)t * BATCH + row] > thr) continue;
        const uchar_t* mb = mask_g + (size_t)row * 1024 + t * 16;
        u64 m0 = *(const u64*)(mb);
        u64 m1 = *(const u64*)(mb + 8);
        while (m0) {                      // byte c at bits [8c,8c+8): code=j*16+c
            const int p = __builtin_ctzll(m0); m0 &= m0 - 1;
            const int code = t * 128 + (p & 7) * 16 + (p >> 3);
            const unsigned pos = atomicAdd(wl_cnt, 1u);
            if (pos < WL_CAP) wl[pos] = ((unsigned)row << 13) | (unsigned)code;
        }
        while (m1) {
            const int p = __builtin_ctzll(m1); m1 &= m1 - 1;
            const int code = t * 128 + (p & 7) * 16 + 8 + (p >> 3);
            const unsigned pos = atomicAdd(wl_cnt, 1u);
            if (pos < WL_CAP) wl[pos] = ((unsigned)row << 13) | (unsigned)code;
        }
    }
}

// ============================================================================
// Kernel D: exact eval. One thread per candidate (grid-stride): bit-identical
// R2/R3 numerics — ascending-k sequential fmaf; S = fl(z2+e2);
// score = fl(S - 2*acc). Winner via u64 atomicMin on (score_bits<<32 | code):
// scores positive => float bits monotone; equal score => lowest code wins.
// ============================================================================
__global__ void vq_exact_kernel(const float* __restrict__ z,
                                const float* __restrict__ cb,
                                const float* __restrict__ e2g,
                                const float* __restrict__ z2g,
                                const unsigned* __restrict__ wl,
                                const unsigned* __restrict__ wl_cnt,
                                u64* __restrict__ packed_best) {
    const unsigned n = min(*wl_cnt, WL_CAP);
    const unsigned stride = gridDim.x * blockDim.x;
    for (unsigned i = blockIdx.x * blockDim.x + threadIdx.x; i < n; i += stride) {
        const unsigned e = wl[i];
        const int row  = e >> 13;
        const int code = e & (NCODES - 1);
        const float4* z4 = (const float4*)(z  + (size_t)row  * DIM);
        const float4* e4 = (const float4*)(cb + (size_t)code * DIM);
        float acc = 0.0f;
        #pragma unroll 8
        for (int k4 = 0; k4 < DIM / 4; ++k4) {
            const float4 a = z4[k4];
            const float4 b = e4[k4];
            acc = fmaf(a.x, b.x, acc);
            acc = fmaf(a.y, b.y, acc);
            acc = fmaf(a.z, b.z, acc);
            acc = fmaf(a.w, b.w, acc);
        }
        const float S  = z2g[row] + e2g[code];
        const float sc = fmaf(-2.0f, acc, S);
        union { float f; unsigned u; } sb; sb.f = sc;
        const u64 packed = ((u64)sb.u << 32) | (unsigned)code;
        atomicMin(&packed_best[row], packed);
    }
}

// ============================================================================
// Kernel E: gather + ST + loss. Reads winner from packed_best; writes idx_f
// and z_q_st = fl(z_e + fl(z_q - z_e)); accumulates squared-error sum.
// ============================================================================
__global__ void vq_gather_loss_kernel(const float* __restrict__ z,
                                      const float* __restrict__ cb,
                                      const u64* __restrict__ packed_best,
                                      float* __restrict__ idx_f,
                                      float* __restrict__ zq_out,
                                      float* __restrict__ loss_acc) {
    const int lane = threadIdx.x & 63;
    const int wid  = threadIdx.x >> 6;
    const int row  = blockIdx.x * 4 + wid;
    const int k = (int)(packed_best[row] & (u64)(NCODES - 1));
    if (lane == 0) idx_f[row] = (float)k;
    const float4 e  = *(const float4*)(cb + (size_t)k * DIM + lane * 4);
    const float4 zv = *(const float4*)(z + (size_t)row * DIM + lane * 4);
    const float dx = e.x - zv.x, dy = e.y - zv.y, dz = e.z - zv.z, dw = e.w - zv.w;
    float4 o;
    o.x = zv.x + dx; o.y = zv.y + dy; o.z = zv.z + dz; o.w = zv.w + dw;
    *(float4*)(zq_out + (size_t)row * DIM + lane * 4) = o;
    float s = dx * dx + dy * dy + dz * dz + dw * dw;
    #pragma unroll
    for (int off = 32; off > 0; off >>= 1) s += __shfl_down(s, off, 64);
    __shared__ float wsum[4];
    if (lane == 0) wsum[wid] = s;
    __syncthreads();
    if (threadIdx.x == 0)
        atomicAdd(loss_acc, wsum[0] + wsum[1] + wsum[2] + wsum[3]);
}

// ============================================================================
// Kernel F: finalize scalars.
// ============================================================================
__global__ void vq_finalize_kernel(const float* __restrict__ loss_acc,
                                   float* __restrict__ out_losses) {
    const float mean = *loss_acc * (1.0f / (float)(BATCH * DIM));  // /2^23 exact
    out_losses[0] = mean + BETA * mean;    // vq_loss
    out_losses[1] = mean;                  // cb_loss
    out_losses[2] = mean;                  // commit_loss
}

// ============================================================================
extern "C" void kernel_launch(void* const* d_in, const int* in_sizes, int n_in,
                              void* d_out, int out_size, void* d_ws, size_t ws_size,
                              hipStream_t stream) {
    const float* z  = (const float*)d_in[0];   // [32768, 256] fp32
    const float* cb = (const float*)d_in[1];   // [8192, 256]  fp32

    float* out    = (float*)d_out;
    float* zq     = out;                                   // [32768*256]
    float* idx_f  = out + (size_t)BATCH * DIM;             // [32768]
    float* losses = out + (size_t)BATCH * DIM + BATCH;     // [3]
    uchar_t* mask = (uchar_t*)d_out;                       // zq region reused: 1 KB/row

    // ws layout (floats): ctrl[256] | e2 | z2 | tilemin(2M) | packed(64K) |
    //                     worklist(1M u32) | zh (u16) | eh (u16)   ~= 33 MB
    float* ws         = (float*)d_ws;
    float* loss_acc   = ws;                                // [0]
    unsigned* wl_cnt  = (unsigned*)(ws + 1);               // [1]
    float* e2         = ws + 256;                          // 8192
    float* z2         = e2 + NCODES;                       // 32768
    float* tilemin    = z2 + BATCH;                        // 64*32768
    u64*   packed     = (u64*)(tilemin + (size_t)64 * BATCH);      // 32768 u64
    unsigned* wl      = (unsigned*)(packed + BATCH);               // 1M u32
    ushort_t* zh      = (ushort_t*)(wl + WL_CAP);                  // 32768*256
    ushort_t* eh      = zh + (size_t)BATCH * DIM;                  // 8192*256

    vq_prep_kernel<<<(NCODES + BATCH) / 4, 256, 0, stream>>>(z, cb, e2, z2, eh, zh, loss_acc, wl_cnt);
    vq_screen_kernel<<<BATCH / 64, 256, 0, stream>>>(zh, eh, e2, tilemin, mask);
    vq_candidates_kernel<<<BATCH / 256, 256, 0, stream>>>(tilemin, mask, wl, wl_cnt, packed);
    vq_exact_kernel<<<1024, 256, 0, stream>>>(z, cb, e2, z2, wl, wl_cnt, packed);
    vq_gather_loss_kernel<<<BATCH / 4, 256, 0, stream>>>(z, cb, packed, idx_f, zq, loss_acc);
    vq_finalize_kernel<<<1, 1, 0, stream>>>(loss_acc, losses);
}

// Round 5
// 605.310 us; speedup vs baseline: 3.8935x; 1.5050x over previous
//
#include <hip/hip_runtime.h>

#define BATCH   32768
#define DIM     256
#define NCODES  8192
#define BETA    0.25f
#define EPS     3e-4f   // screen window: grid-tie ulp + 2*delta(bf16 screen) + bf16-tilemin fuzz
#define SLOTS   64      // per-row deterministic worklist slots
#define OVF_CAP (1u << 17)

typedef unsigned short ushort_t;
typedef unsigned char  uchar_t;
typedef unsigned long long u64;
typedef __attribute__((ext_vector_type(8))) short bf16x8;
typedef __attribute__((ext_vector_type(4))) float f32x4;

// async global->LDS, 16B per lane; dest = wave-uniform base + lane*16
#define GLOAD16(gp, lp) __builtin_amdgcn_global_load_lds( \
    (const __attribute__((address_space(1))) void*)(gp), \
    (__attribute__((address_space(3))) void*)(lp), 16, 0, 0)

__device__ inline ushort_t f2bf(float f) {  // RNE float->bf16 (no NaN in data)
    union { float f; unsigned u; } v; v.f = f;
    return (ushort_t)((v.u + 0x7FFF + ((v.u >> 16) & 1)) >> 16);
}
__device__ inline ushort_t f2bf_rd(float f) {  // round toward -inf (conservative tilemin)
    union { float f; unsigned u; } v; v.f = f;
    unsigned u = v.u;
    if (f < 0.0f) u += 0xFFFFu;   // magnitude up for negatives => value down
    return (ushort_t)(u >> 16);
}

// ============================================================================
// Kernel A: fused prep. One wave per row (codebook rows then z rows):
// e2[k]/z2[b] row sums-of-squares + bf16 copies eh/zh. Zeroes loss acc and
// the overflow counter (d_ws is poisoned 0xAA every launch).
// ============================================================================
__global__ void vq_prep_kernel(const float* __restrict__ z,
                               const float* __restrict__ cb,
                               float* __restrict__ e2, float* __restrict__ z2,
                               ushort_t* __restrict__ eh, ushort_t* __restrict__ zh,
                               float* __restrict__ loss_acc,
                               unsigned* __restrict__ ovf_cnt) {
    const int lane = threadIdx.x & 63;
    const int wid  = threadIdx.x >> 6;
    const int item = blockIdx.x * 4 + wid;
    const float* src;
    ushort_t* dst;
    if (item < NCODES) { src = cb + (size_t)item * DIM;            dst = eh + (size_t)item * DIM; }
    else               { src = z  + (size_t)(item - NCODES) * DIM; dst = zh + (size_t)(item - NCODES) * DIM; }
    const float4 v = *(const float4*)(src + lane * 4);
    ushort4 b; b.x = f2bf(v.x); b.y = f2bf(v.y); b.z = f2bf(v.z); b.w = f2bf(v.w);
    *(ushort4*)(dst + lane * 4) = b;
    float s = v.x * v.x + v.y * v.y + v.z * v.z + v.w * v.w;
    #pragma unroll
    for (int off = 32; off > 0; off >>= 1) s += __shfl_down(s, off, 64);
    if (lane == 0) {
        if (item < NCODES) e2[item] = s;
        else               z2[item - NCODES] = s;
    }
    if (blockIdx.x == 0 && threadIdx.x == 0) { *loss_acc = 0.0f; *ovf_cnt = 0u; }
}

// ============================================================================
// Kernel B: MFMA screen. approx score s = e2[c] - 2*(zh.eh), bf16 MFMA
// fp32-acc. Per (row, 128-code tile): tile-min (bf16 round-down, layout
// [row][tile] for wave-coalesced reads downstream) and a 128-bit mask of
// codes with s <= tilemin + EPS (in d_out's zq region, overwritten later).
// ============================================================================
__launch_bounds__(256, 2)
__global__ void vq_screen_kernel(const ushort_t* __restrict__ zh_g,
                                 const ushort_t* __restrict__ eh_g,
                                 const float* __restrict__ e2g,
                                 ushort_t* __restrict__ tilemin_g,
                                 uchar_t* __restrict__ mask_g) {
    __shared__ ushort_t zh_s[64 * 32];    // 4 row-tiles of [16][32]
    __shared__ ushort_t eh_s[512 * 32];   // 32 code-tiles of [16][32]
    __shared__ float    e2_s[512];

    const int t    = threadIdx.x;
    const int w    = t >> 6;        // wave 0..3
    const int lane = t & 63;
    const int c    = lane & 15;     // MFMA col / fragment row
    const int q    = lane >> 4;     // MFMA quad
    const int row0 = blockIdx.x * 64;

    for (int ct = 0; ct < 16; ++ct) {
        __syncthreads();                       // prev epilogue done before e2_s restage
        e2_s[t]       = e2g[ct * 512 + t];
        e2_s[256 + t] = e2g[ct * 512 + 256 + t];

        f32x4 acc[4][8];
        #pragma unroll
        for (int i = 0; i < 4; ++i)
            #pragma unroll
            for (int j = 0; j < 8; ++j) acc[i][j] = (f32x4)0.0f;

        for (int kc = 0; kc < 256; kc += 32) {
            __syncthreads();                   // prev chunk's frag reads done
            GLOAD16(zh_g + (size_t)(row0 + w * 16 + (lane >> 2)) * DIM + kc + (lane & 3) * 8,
                    &zh_s[w * 512]);
            #pragma unroll
            for (int s8 = 0; s8 < 8; ++s8) {
                const int c16 = w * 8 + s8;
                GLOAD16(eh_g + (size_t)(ct * 512 + c16 * 16 + (lane >> 2)) * DIM + kc + (lane & 3) * 8,
                        &eh_s[c16 * 512]);
            }
            __syncthreads();                   // vmcnt(0) drain + visibility

            bf16x8 a[4], b[8];
            #pragma unroll
            for (int i = 0; i < 4; ++i)
                a[i] = *(const bf16x8*)&zh_s[i * 512 + c * 32 + q * 8];
            #pragma unroll
            for (int j = 0; j < 8; ++j)
                b[j] = *(const bf16x8*)&eh_s[(w * 8 + j) * 512 + c * 32 + q * 8];
            #pragma unroll
            for (int i = 0; i < 4; ++i)
                #pragma unroll
                for (int j = 0; j < 8; ++j)
                    acc[i][j] = __builtin_amdgcn_mfma_f32_16x16x32_bf16(a[i], b[j], acc[i][j], 0, 0, 0);
        }

        // epilogue: scores, per-row tile min, mask bits
        float tm[4][4];
        #pragma unroll
        for (int i = 0; i < 4; ++i)
            #pragma unroll
            for (int reg = 0; reg < 4; ++reg) tm[i][reg] = 3.4e38f;
        #pragma unroll
        for (int i = 0; i < 4; ++i)
            #pragma unroll
            for (int j = 0; j < 8; ++j) {
                const float e2v = e2_s[w * 128 + j * 16 + c];
                #pragma unroll
                for (int reg = 0; reg < 4; ++reg) {
                    const float s = fmaf(-2.0f, acc[i][j][reg], e2v);
                    acc[i][j][reg] = s;
                    tm[i][reg] = fminf(tm[i][reg], s);
                }
            }
        #pragma unroll
        for (int st = 1; st < 16; st <<= 1)
            #pragma unroll
            for (int i = 0; i < 4; ++i)
                #pragma unroll
                for (int reg = 0; reg < 4; ++reg)
                    tm[i][reg] = fminf(tm[i][reg], __shfl_xor(tm[i][reg], st, 64));

        const int tile = ct * 4 + w;
        #pragma unroll
        for (int i = 0; i < 4; ++i)
            #pragma unroll
            for (int reg = 0; reg < 4; ++reg) {
                const int row = row0 + i * 16 + q * 4 + reg;
                const float thr = tm[i][reg] + EPS;
                unsigned m8 = 0;
                #pragma unroll
                for (int j = 0; j < 8; ++j)
                    m8 |= (unsigned)(acc[i][j][reg] <= thr) << j;
                mask_g[(size_t)row * 1024 + tile * 16 + c] = (uchar_t)m8;
                if (c == 0) tilemin_g[(size_t)row * 64 + tile] = f2bf_rd(tm[i][reg]);
            }
    }
}

// ============================================================================
// Kernel C: candidate emission, ONE WAVE PER ROW (lane = tile). Coalesced
// tile-min load, butterfly gmin, active lanes read only their tile's mask,
// 64-lane prefix scan assigns deterministic slots in wl16[row][0..64).
// No shared-counter atomics (R4's 444us was 530k same-address atomicAdds);
// rare >SLOTS overflow spills to a small atomic list.
// ============================================================================
__global__ void vq_candidates_kernel(const ushort_t* __restrict__ tilemin_g,
                                     const uchar_t* __restrict__ mask_g,
                                     unsigned* __restrict__ cnt_g,
                                     ushort_t* __restrict__ wl16,
                                     unsigned* __restrict__ ovf,
                                     unsigned* __restrict__ ovf_cnt,
                                     u64* __restrict__ packed_best) {
    const int lane = threadIdx.x & 63;
    const int row  = blockIdx.x * 4 + (threadIdx.x >> 6);

    union { unsigned u; float f; } tv;
    tv.u = ((unsigned)tilemin_g[(size_t)row * 64 + lane]) << 16;
    const float tm = tv.f;
    float gmin = tm;
    #pragma unroll
    for (int d = 32; d > 0; d >>= 1) gmin = fminf(gmin, __shfl_xor(gmin, d, 64));
    const float thr = gmin + EPS;

    u64 m0 = 0, m1 = 0;
    if (tm <= thr) {
        const uchar_t* mb = mask_g + (size_t)row * 1024 + lane * 16;
        m0 = *(const u64*)(mb);
        m1 = *(const u64*)(mb + 8);
    }
    const unsigned cnt = __popcll(m0) + __popcll(m1);
    unsigned inc = cnt;
    #pragma unroll
    for (int d = 1; d < 64; d <<= 1) {
        const unsigned o = __shfl_up(inc, d, 64);
        if (lane >= d) inc += o;
    }
    const unsigned excl  = inc - cnt;
    const unsigned total = __shfl(inc, 63, 64);
    if (lane == 0) {
        cnt_g[row] = total < SLOTS ? total : SLOTS;
        packed_best[row] = ~0ull;
    }
    // emit: byte c at bits [8c,8c+8) -> code = tile*128 + j*16 + c
    unsigned slot = excl;
    while (m0) {
        const int p = __builtin_ctzll(m0); m0 &= m0 - 1;
        const unsigned code = lane * 128 + (p & 7) * 16 + (p >> 3);
        if (slot < SLOTS) wl16[(size_t)row * SLOTS + slot] = (ushort_t)code;
        else { const unsigned pos = atomicAdd(ovf_cnt, 1u);
               if (pos < OVF_CAP) ovf[pos] = ((unsigned)row << 13) | code; }
        ++slot;
    }
    while (m1) {
        const int p = __builtin_ctzll(m1); m1 &= m1 - 1;
        const unsigned code = lane * 128 + (p & 7) * 16 + 8 + (p >> 3);
        if (slot < SLOTS) wl16[(size_t)row * SLOTS + slot] = (ushort_t)code;
        else { const unsigned pos = atomicAdd(ovf_cnt, 1u);
               if (pos < OVF_CAP) ovf[pos] = ((unsigned)row << 13) | code; }
        ++slot;
    }
}

// ============================================================================
// Kernel D: exact eval, one thread per (row, slot) + grid-stride overflow.
// Bit-identical R2 numerics: ascending-k sequential fmaf; S = fl(z2+e2);
// score = fl(S - 2*acc). Winner via u64 atomicMin on (score_bits<<32 | code):
// scores positive => float bits monotone; equal score => lowest code wins.
// ============================================================================
__global__ void vq_exact_kernel(const float* __restrict__ z,
                                const float* __restrict__ cb,
                                const float* __restrict__ e2g,
                                const float* __restrict__ z2g,
                                const unsigned* __restrict__ cnt_g,
                                const ushort_t* __restrict__ wl16,
                                const unsigned* __restrict__ ovf,
                                const unsigned* __restrict__ ovf_cnt,
                                u64* __restrict__ packed_best) {
    const unsigned tid = blockIdx.x * 256 + threadIdx.x;   // grid = BATCH*SLOTS threads
    {
        const int row = tid >> 6;
        const int s   = tid & (SLOTS - 1);
        if (s < (int)cnt_g[row]) {
            const int code = wl16[(size_t)row * SLOTS + s];
            const float4* z4 = (const float4*)(z  + (size_t)row  * DIM);
            const float4* e4 = (const float4*)(cb + (size_t)code * DIM);
            float acc = 0.0f;
            #pragma unroll 8
            for (int k4 = 0; k4 < DIM / 4; ++k4) {
                const float4 a = z4[k4];
                const float4 b = e4[k4];
                acc = fmaf(a.x, b.x, acc);
                acc = fmaf(a.y, b.y, acc);
                acc = fmaf(a.z, b.z, acc);
                acc = fmaf(a.w, b.w, acc);
            }
            const float S  = z2g[row] + e2g[code];
            const float sc = fmaf(-2.0f, acc, S);
            union { float f; unsigned u; } sb; sb.f = sc;
            atomicMin(&packed_best[row], ((u64)sb.u << 32) | (unsigned)code);
        }
    }
    // overflow entries (normally zero)
    const unsigned n = min(*ovf_cnt, OVF_CAP);
    for (unsigned i = tid; i < n; i += gridDim.x * 256) {
        const unsigned e = ovf[i];
        const int row  = e >> 13;
        const int code = e & (NCODES - 1);
        const float4* z4 = (const float4*)(z  + (size_t)row  * DIM);
        const float4* e4 = (const float4*)(cb + (size_t)code * DIM);
        float acc = 0.0f;
        #pragma unroll 8
        for (int k4 = 0; k4 < DIM / 4; ++k4) {
            const float4 a = z4[k4];
            const float4 b = e4[k4];
            acc = fmaf(a.x, b.x, acc);
            acc = fmaf(a.y, b.y, acc);
            acc = fmaf(a.z, b.z, acc);
            acc = fmaf(a.w, b.w, acc);
        }
        const float S  = z2g[row] + e2g[code];
        const float sc = fmaf(-2.0f, acc, S);
        union { float f; unsigned u; } sb; sb.f = sc;
        atomicMin(&packed_best[row], ((u64)sb.u << 32) | (unsigned)code);
    }
}

// ============================================================================
// Kernel E: gather + ST + loss. z_q_st = fl(z_e + fl(z_q - z_e)).
// ============================================================================
__global__ void vq_gather_loss_kernel(const float* __restrict__ z,
                                      const float* __restrict__ cb,
                                      const u64* __restrict__ packed_best,
                                      float* __restrict__ idx_f,
                                      float* __restrict__ zq_out,
                                      float* __restrict__ loss_acc) {
    const int lane = threadIdx.x & 63;
    const int wid  = threadIdx.x >> 6;
    const int row  = blockIdx.x * 4 + wid;
    const int k = (int)(packed_best[row] & (u64)(NCODES - 1));
    if (lane == 0) idx_f[row] = (float)k;
    const float4 e  = *(const float4*)(cb + (size_t)k * DIM + lane * 4);
    const float4 zv = *(const float4*)(z + (size_t)row * DIM + lane * 4);
    const float dx = e.x - zv.x, dy = e.y - zv.y, dz = e.z - zv.z, dw = e.w - zv.w;
    float4 o;
    o.x = zv.x + dx; o.y = zv.y + dy; o.z = zv.z + dz; o.w = zv.w + dw;
    *(float4*)(zq_out + (size_t)row * DIM + lane * 4) = o;
    float s = dx * dx + dy * dy + dz * dz + dw * dw;
    #pragma unroll
    for (int off = 32; off > 0; off >>= 1) s += __shfl_down(s, off, 64);
    __shared__ float wsum[4];
    if (lane == 0) wsum[wid] = s;
    __syncthreads();
    if (threadIdx.x == 0)
        atomicAdd(loss_acc, wsum[0] + wsum[1] + wsum[2] + wsum[3]);
}

// ============================================================================
// Kernel F: finalize scalars.
// ============================================================================
__global__ void vq_finalize_kernel(const float* __restrict__ loss_acc,
                                   float* __restrict__ out_losses) {
    const float mean = *loss_acc * (1.0f / (float)(BATCH * DIM));  // /2^23 exact
    out_losses[0] = mean + BETA * mean;    // vq_loss
    out_losses[1] = mean;                  // cb_loss
    out_losses[2] = mean;                  // commit_loss
}

// ============================================================================
extern "C" void kernel_launch(void* const* d_in, const int* in_sizes, int n_in,
                              void* d_out, int out_size, void* d_ws, size_t ws_size,
                              hipStream_t stream) {
    const float* z  = (const float*)d_in[0];   // [32768, 256] fp32
    const float* cb = (const float*)d_in[1];   // [8192, 256]  fp32

    float* out    = (float*)d_out;
    float* zq     = out;                                   // [32768*256]
    float* idx_f  = out + (size_t)BATCH * DIM;             // [32768]
    float* losses = out + (size_t)BATCH * DIM + BATCH;     // [3]
    uchar_t* mask = (uchar_t*)d_out;                       // zq region reused: 1 KB/row

    // ws layout (~29 MB; R4's proven-safe bound was 32.4 MB):
    // ctrl[256 f] | e2 | z2 | cnt(u32) | packed(u64) | tilemin(u16) |
    // wl16(u16) | ovf(u32) | zh(u16) | eh(u16)
    float*    ws        = (float*)d_ws;
    float*    loss_acc  = ws;                                       // [0]
    unsigned* ovf_cnt   = (unsigned*)(ws + 1);                      // [1]
    float*    e2        = ws + 256;                                 // 8192 f
    float*    z2        = e2 + NCODES;                              // 32768 f
    unsigned* cnt       = (unsigned*)(z2 + BATCH);                  // 32768 u32
    u64*      packed    = (u64*)(cnt + BATCH);                      // 32768 u64
    ushort_t* tilemin   = (ushort_t*)(packed + BATCH);              // 32768*64 u16
    ushort_t* wl16      = tilemin + (size_t)BATCH * 64;             // 32768*64 u16
    unsigned* ovf       = (unsigned*)(wl16 + (size_t)BATCH * SLOTS);// 128K u32
    ushort_t* zh        = (ushort_t*)(ovf + OVF_CAP);               // 32768*256 u16
    ushort_t* eh        = zh + (size_t)BATCH * DIM;                 // 8192*256 u16

    vq_prep_kernel<<<(NCODES + BATCH) / 4, 256, 0, stream>>>(z, cb, e2, z2, eh, zh, loss_acc, ovf_cnt);
    vq_screen_kernel<<<BATCH / 64, 256, 0, stream>>>(zh, eh, e2, tilemin, mask);
    vq_candidates_kernel<<<BATCH / 4, 256, 0, stream>>>(tilemin, mask, cnt, wl16, ovf, ovf_cnt, packed);
    vq_exact_kernel<<<BATCH * SLOTS / 256, 256, 0, stream>>>(z, cb, e2, z2, cnt, wl16, ovf, ovf_cnt, packed);
    vq_gather_loss_kernel<<<BATCH / 4, 256, 0, stream>>>(z, cb, packed, idx_f, zq, loss_acc);
    vq_finalize_kernel<<<1, 1, 0, stream>>>(loss_acc, losses);
}